// Round 8
// baseline (414.635 us; speedup 1.0000x reference)
//
#include <hip/hip_runtime.h>
#include <math.h>

#define HDIM 768
#define RDIM 64
#define NEXP 8
#define NTOK 16384

typedef _Float16 half8 __attribute__((ext_vector_type(8)));
typedef float float4_t __attribute__((ext_vector_type(4)));

__device__ __forceinline__ float gelu_exact(float v) {
    return 0.5f * v * (1.0f + erff(v * 0.70710678118654752440f));
}

// ---------------------------------------------------------------------------
// routerprep: ONE launch, two disjoint block roles (no cross-block deps):
//   blocks 0..1023   : router v4 (R6-proven body), with the fused router
//                      weight wrl[8][768] built IN-LDS from enc_w/sw_w
//                      (same fp32 r-ordered sum as old prep -> bit-identical
//                      logits). Removes the router->prep dependency.
//   blocks 1024..1407: w1t/w2t f16 transposes (old prep, 1536 waves).
// This cuts the serial chain from 5 dispatches to 4 and hides prep's
// duration under the router's 50MB x-stream. enc_w re-reads (196KB x 1024
// blocks = 200MB) are L2/L3-resident: ~6us aggregate, hidden.
// NOTE R7: cooperative mega-kernel (grid.sync) hangs the container; this is
// the no-device-sync version of the same overhead reduction.
// ---------------------------------------------------------------------------
__global__ __launch_bounds__(256, 4) void routerprep_kernel(
    const float* __restrict__ x, const float* __restrict__ enc_w,
    const float* __restrict__ enc_b, const float* __restrict__ sw_w,
    const float* __restrict__ sw_b, const float* __restrict__ w1,
    const float* __restrict__ w2, _Float16* __restrict__ w1t,
    _Float16* __restrict__ w2t, float* __restrict__ pmax,
    int* __restrict__ counts, int* __restrict__ lists)
{
    const int bid = blockIdx.x;
    const int tid = threadIdx.x;
    const int wv = tid >> 6, lane = tid & 63;

    if (bid >= 1024) {
        // ================= prep role: w1t/w2t transposes =================
        const int wid = (bid - 1024) * 4 + wv;     // 0..1535
        if (wid < 768) {
            const int e = wid / 96, k0 = (wid % 96) * 8;
            half8 o;
            #pragma unroll
            for (int j = 0; j < 8; j++)
                o[j] = (_Float16)w1[((size_t)(e * HDIM + k0 + j)) * RDIM + lane];
            *(half8*)(w1t + ((size_t)(e * RDIM + lane)) * HDIM + k0) = o;
        } else {
            const int id = wid - 768;
            const int e = id / 96, rem = id % 96;
            const int n = (rem >> 3) * 64 + lane, k0 = (rem & 7) * 8;
            half8 o;
            #pragma unroll
            for (int j = 0; j < 8; j++)
                o[j] = (_Float16)w2[((size_t)(e * RDIM + k0 + j)) * HDIM + n];
            *(half8*)(w2t + ((size_t)(e * HDIM + n)) * RDIM + k0) = o;
        }
        return;
    }

    // ================= router role =================
    __shared__ __align__(16) float wrl[NEXP][772];
    __shared__ __align__(16) float sws[512];
    __shared__ float brl[NEXP];
    __shared__ int lcnt[NEXP], gbase[NEXP];

    // stage sw_w (512 floats)
    if (tid < 128) ((float4*)sws)[tid] = ((const float4*)sw_w)[tid];
    if (tid < NEXP) lcnt[tid] = 0;
    __syncthreads();

    // build wrl: thread handles k = tid + j*256 (j=0..2), all 8 experts.
    // fp32, r-ordered sum == old prep_kernel -> bit-identical logits.
    #pragma unroll
    for (int j = 0; j < 3; j++) {
        const int k = tid + j * 256;
        float4 row[16];
        #pragma unroll
        for (int u = 0; u < 16; u++)
            row[u] = *(const float4*)(enc_w + (size_t)k * RDIM + u * 4);
        #pragma unroll
        for (int e = 0; e < 8; e++) {
            float s = 0.0f;
            #pragma unroll
            for (int u = 0; u < 16; u++) {
                s = fmaf(row[u].x, sws[(u * 4 + 0) * 8 + e], s);
                s = fmaf(row[u].y, sws[(u * 4 + 1) * 8 + e], s);
                s = fmaf(row[u].z, sws[(u * 4 + 2) * 8 + e], s);
                s = fmaf(row[u].w, sws[(u * 4 + 3) * 8 + e], s);
            }
            wrl[e][k] = s;
        }
    }
    if (tid < NEXP) {
        float s = sw_b[tid];
        #pragma unroll 16
        for (int r = 0; r < RDIM; r++)
            s += enc_b[r] * sws[r * NEXP + tid];
        brl[tid] = s;
    }
    __syncthreads();

    const int hh = lane & 31, hw = lane >> 5;
    float br[8];
    #pragma unroll
    for (int e = 0; e < 8; e++) br[e] = brl[e];

    int amv[2], lpv[2], tkv[2];
    #pragma unroll
    for (int it = 0; it < 2; it++) {
        const int tok = bid * 16 + it * 8 + wv * 2 + hw;
        const float* xrow = x + (size_t)tok * HDIM;
        float4 xv[6];
        #pragma unroll
        for (int g = 0; g < 6; g++)
            xv[g] = *(const float4*)(xrow + g * 128 + hh * 4);

        float acc[8];
        #pragma unroll
        for (int e = 0; e < 8; e++) acc[e] = 0.0f;
        #pragma unroll
        for (int e = 0; e < 8; e++) {
            #pragma unroll
            for (int g = 0; g < 6; g++) {
                const float4 w4 = *(const float4*)&wrl[e][g * 128 + hh * 4];
                acc[e] = fmaf(xv[g].x, w4.x, acc[e]);
                acc[e] = fmaf(xv[g].y, w4.y, acc[e]);
                acc[e] = fmaf(xv[g].z, w4.z, acc[e]);
                acc[e] = fmaf(xv[g].w, w4.w, acc[e]);
            }
        }
        #pragma unroll
        for (int d = 1; d < 32; d <<= 1) {
            #pragma unroll
            for (int e = 0; e < 8; e++)
                acc[e] += __shfl_xor(acc[e], d);
        }
        float lg[8];
        lg[0] = acc[0] + br[0];
        float m = lg[0]; int am = 0;
        #pragma unroll
        for (int e = 1; e < 8; e++) {
            lg[e] = acc[e] + br[e];
            if (lg[e] > m) { m = lg[e]; am = e; }
        }
        float s = 0.0f;
        #pragma unroll
        for (int e = 0; e < 8; e++) s += expf(lg[e] - m);

        amv[it] = -1;
        if (hh == 0) {
            pmax[tok] = 1.0f / s;
            amv[it] = am;
            lpv[it] = atomicAdd(&lcnt[am], 1);
            tkv[it] = tok;
        }
    }
    __syncthreads();
    if (tid < NEXP) gbase[tid] = atomicAdd(&counts[tid * 32], lcnt[tid]);
    __syncthreads();
    #pragma unroll
    for (int it = 0; it < 2; it++)
        if (amv[it] >= 0)
            lists[amv[it] * NTOK + gbase[amv[it]] + lpv[it]] = tkv[it];
}

// ---------------------------------------------------------------------------
// mm1 (R6-proven, unchanged): K-split across 4 waves, hoisted x loads.
// ---------------------------------------------------------------------------
__global__ __launch_bounds__(256, 4) void mm1_kernel(
    const float* __restrict__ x, const _Float16* __restrict__ w1t,
    const float* __restrict__ b1, const int* __restrict__ counts,
    const int* __restrict__ lists, _Float16* __restrict__ h)
{
    __shared__ __align__(16) float part[4][16][68];

    const int e = blockIdx.x;
    const int cnt = counts[e * 32];
    const int tid = threadIdx.x;
    const int wv = tid >> 6, lane = tid & 63;
    const int q = lane >> 4, c = lane & 15;

    for (int st = blockIdx.y; st * 16 < cnt; st += gridDim.y) {
        const int base = st * 16;
        const int nt = cnt - base;
        const int tA = lists[e * NTOK + base + min(c, nt - 1)];
        const float* xrow = x + (size_t)tA * HDIM + wv * 192;
        const _Float16* wbase = w1t + ((size_t)(e * RDIM + c)) * HDIM + wv * 192 + q * 8;

        float4 xv[12];
        #pragma unroll
        for (int it = 0; it < 6; it++) {
            xv[2 * it]     = *(const float4*)(xrow + it * 32 + q * 8);
            xv[2 * it + 1] = *(const float4*)(xrow + it * 32 + q * 8 + 4);
        }

        float4_t acc[4] = {{0,0,0,0},{0,0,0,0},{0,0,0,0},{0,0,0,0}};
        #pragma unroll
        for (int it = 0; it < 6; it++) {
            const int k0 = it * 32;
            half8 a;
            a[0] = (_Float16)xv[2*it].x;   a[1] = (_Float16)xv[2*it].y;
            a[2] = (_Float16)xv[2*it].z;   a[3] = (_Float16)xv[2*it].w;
            a[4] = (_Float16)xv[2*it+1].x; a[5] = (_Float16)xv[2*it+1].y;
            a[6] = (_Float16)xv[2*it+1].z; a[7] = (_Float16)xv[2*it+1].w;
            #pragma unroll
            for (int nf = 0; nf < 4; nf++) {
                half8 b = *(const half8*)(wbase + (size_t)nf * 16 * HDIM + k0);
                acc[nf] = __builtin_amdgcn_mfma_f32_16x16x32_f16(a, b, acc[nf], 0, 0, 0);
            }
        }

        #pragma unroll
        for (int nf = 0; nf < 4; nf++)
            #pragma unroll
            for (int i = 0; i < 4; i++)
                part[wv][q * 4 + i][nf * 16 + c] = acc[nf][i];
        __syncthreads();

        #pragma unroll
        for (int j = 0; j < 4; j++) {
            const int idx = tid + 256 * j;
            const int row = idx >> 6, r = idx & 63;
            if (row < nt) {
                const int tok = lists[e * NTOK + base + row];
                float v = part[0][row][r] + part[1][row][r] + part[2][row][r]
                        + part[3][row][r] + b1[e * RDIM + r];
                h[(size_t)tok * RDIM + r] = (_Float16)gelu_exact(v);
            }
        }
        __syncthreads();   // part reused next strip
    }
}

// ---------------------------------------------------------------------------
// mm2 (R6-proven, unchanged): LDS-free, barrier-free.
// ---------------------------------------------------------------------------
__global__ __launch_bounds__(256, 3) void mm2_kernel(
    const _Float16* __restrict__ h, const _Float16* __restrict__ w2t,
    const float* __restrict__ b2, const float* __restrict__ pmax,
    const int* __restrict__ counts, const int* __restrict__ lists,
    float* __restrict__ out)
{
    const int e = blockIdx.x;
    const int cnt = counts[e * 32];
    const int wv = threadIdx.x >> 6, lane = threadIdx.x & 63;
    const int q = lane >> 4, c = lane & 15;

    const int task = blockIdx.y * 4 + wv;   // 0..383
    const int nch = task % 3;
    const int sidx = task / 3;              // 0..127

    for (int st = sidx; st * 16 < cnt; st += 128) {
        const int base = st * 16;
        const int nt = cnt - base;
        const int tA = lists[e * NTOK + base + min(c, nt - 1)];
        half8 a0 = *(const half8*)(h + (size_t)tA * RDIM + q * 8);
        half8 a1 = *(const half8*)(h + (size_t)tA * RDIM + 32 + q * 8);

        int tokv[4]; float pm[4]; bool ok[4];
        #pragma unroll
        for (int i = 0; i < 4; i++) {
            const int row = q * 4 + i;
            ok[i] = row < nt;
            tokv[i] = lists[e * NTOK + base + min(row, nt - 1)];
            pm[i] = pmax[tokv[i]];
        }

        #pragma unroll 4
        for (int nf = 0; nf < 16; nf++) {
            const int n = nch * 256 + nf * 16 + c;
            const _Float16* wrow = w2t + ((size_t)(e * HDIM + n)) * RDIM;
            half8 b0 = *(const half8*)(wrow + q * 8);
            half8 b1v = *(const half8*)(wrow + 32 + q * 8);
            float4_t acc = {0, 0, 0, 0};
            acc = __builtin_amdgcn_mfma_f32_16x16x32_f16(a0, b0, acc, 0, 0, 0);
            acc = __builtin_amdgcn_mfma_f32_16x16x32_f16(a1, b1v, acc, 0, 0, 0);
            const float b2v = b2[e * HDIM + n];
            #pragma unroll
            for (int i = 0; i < 4; i++) {
                if (ok[i])
                    out[(size_t)tokv[i] * HDIM + n] = (acc[i] + b2v) * pm[i];
            }
        }
    }
}

extern "C" void kernel_launch(void* const* d_in, const int* in_sizes, int n_in,
                              void* d_out, int out_size, void* d_ws, size_t ws_size,
                              hipStream_t stream) {
    const float* x     = (const float*)d_in[0];
    const float* enc_w = (const float*)d_in[1];
    const float* enc_b = (const float*)d_in[2];
    const float* sw_w  = (const float*)d_in[3];
    const float* sw_b  = (const float*)d_in[4];
    const float* w1    = (const float*)d_in[5];
    const float* b1    = (const float*)d_in[6];
    const float* w2    = (const float*)d_in[7];
    const float* b2    = (const float*)d_in[8];
    float* out = (float*)d_out;

    // ws layout (~4.2 MB):
    //   [0,1K)          counts (8 ints, 128B stride)
    //   [1K,66560)      pmax 16384 f32
    //   [66560,590848)  lists 8*16384 i32
    //   [590848,...)    w1t (768K), w2t (768K), h (2M)
    char* p = (char*)d_ws;
    int*      counts = (int*)p;
    float*    pmax   = (float*)(p + 1024);
    int*      lists  = (int*)(p + 66560);
    _Float16* w1t    = (_Float16*)(p + 590848);
    _Float16* w2t    = (_Float16*)(p + 1377280);
    _Float16* h      = (_Float16*)(p + 2163712);

    hipMemsetAsync(d_ws, 0, 1024, stream);

    hipLaunchKernelGGL(routerprep_kernel, dim3(1408), dim3(256), 0, stream,
                       x, enc_w, enc_b, sw_w, sw_b, w1, w2,
                       w1t, w2t, pmax, counts, lists);
    hipLaunchKernelGGL(mm1_kernel, dim3(NEXP, 128), dim3(256), 0, stream,
                       x, w1t, b1, counts, lists, h);
    hipLaunchKernelGGL(mm2_kernel, dim3(NEXP, 96), dim3(256), 0, stream,
                       h, w2t, b2, pmax, counts, lists, out);
}

// Round 9
// 184.912 us; speedup vs baseline: 2.2423x; 2.2423x over previous
//
#include <hip/hip_runtime.h>
#include <math.h>

#define HDIM 768
#define RDIM 64
#define NEXP 8
#define NTOK 16384

typedef _Float16 half8 __attribute__((ext_vector_type(8)));
typedef float float4_t __attribute__((ext_vector_type(4)));

__device__ __forceinline__ float gelu_exact(float v) {
    return 0.5f * v * (1.0f + erff(v * 0.70710678118654752440f));
}

// ---------------------------------------------------------------------------
// prep (R6-proven, unchanged): weight transposes/casts + fused router weight.
//   w1t[e][r][k] = (f16)w1[e][k][r]
//   w2t[e][n][k] = (f16)w2[e][k][n]
//   wrt[e][k]    = sum_r enc_w[k][r]*sw_w[r][e]
//   brr[e]       = sw_b[e] + sum_r enc_b[r]*sw_w[r][e]
// (R8 lesson: do NOT recompute wrt per router block — register spill storm.)
// ---------------------------------------------------------------------------
__global__ __launch_bounds__(256) void prep_kernel(
    const float* __restrict__ w1, const float* __restrict__ w2,
    const float* __restrict__ enc_w, const float* __restrict__ enc_b,
    const float* __restrict__ sw_w, const float* __restrict__ sw_b,
    _Float16* __restrict__ w1t, _Float16* __restrict__ w2t,
    float* __restrict__ wrt, float* __restrict__ brr)
{
    const int wid = blockIdx.x * 4 + (threadIdx.x >> 6);
    const int lane = threadIdx.x & 63;
    if (wid < 768) {
        const int e = wid / 96, k0 = (wid % 96) * 8;
        half8 o;
        #pragma unroll
        for (int j = 0; j < 8; j++)
            o[j] = (_Float16)w1[((size_t)(e * HDIM + k0 + j)) * RDIM + lane];
        *(half8*)(w1t + ((size_t)(e * RDIM + lane)) * HDIM + k0) = o;
    } else if (wid < 1536) {
        const int id = wid - 768;
        const int e = id / 96, rem = id % 96;
        const int n = (rem >> 3) * 64 + lane, k0 = (rem & 7) * 8;
        half8 o;
        #pragma unroll
        for (int j = 0; j < 8; j++)
            o[j] = (_Float16)w2[((size_t)(e * RDIM + k0 + j)) * HDIM + n];
        *(half8*)(w2t + ((size_t)(e * HDIM + n)) * RDIM + k0) = o;
    } else if (wid < 1632) {
        const int k = (wid - 1536) * 8 + (lane >> 3);
        const int e = lane & 7;
        float s = 0.0f;
        #pragma unroll 16
        for (int r = 0; r < RDIM; r++)
            s += enc_w[(size_t)k * RDIM + r] * sw_w[r * NEXP + e];
        wrt[e * HDIM + k] = s;
    } else if (wid == 1632) {
        if (lane < NEXP) {
            float s = sw_b[lane];
            #pragma unroll 16
            for (int r = 0; r < RDIM; r++)
                s += enc_b[r] * sw_w[r * NEXP + lane];
            brr[lane] = s;
        }
    }
}

// ---------------------------------------------------------------------------
// router v4 (R6-proven, unchanged): coalesced split-K matvec.
// ---------------------------------------------------------------------------
__global__ __launch_bounds__(256, 4) void router_kernel(
    const float* __restrict__ x, const float* __restrict__ wrt,
    const float* __restrict__ brr, float* __restrict__ pmax,
    int* __restrict__ counts, int* __restrict__ lists)
{
    __shared__ __align__(16) float wrl[NEXP][772];
    __shared__ int lcnt[NEXP], gbase[NEXP];

    const int tid = threadIdx.x;
    #pragma unroll
    for (int i0 = 0; i0 < 6; i0++) {
        const int i = tid + i0 * 256;
        const int e = i / 192, k4 = (i % 192) * 4;
        *(float4*)&wrl[e][k4] = *(const float4*)(wrt + e * HDIM + k4);
    }
    if (tid < NEXP) lcnt[tid] = 0;

    const int wv = tid >> 6, lane = tid & 63;
    const int h = lane & 31, hw = lane >> 5;

    float br[8];
    #pragma unroll
    for (int e = 0; e < 8; e++) br[e] = brr[e];
    __syncthreads();

    int amv[2], lpv[2], tkv[2];
    #pragma unroll
    for (int it = 0; it < 2; it++) {
        const int tok = blockIdx.x * 16 + it * 8 + wv * 2 + hw;
        const float* xrow = x + (size_t)tok * HDIM;
        float4 xv[6];
        #pragma unroll
        for (int g = 0; g < 6; g++)
            xv[g] = *(const float4*)(xrow + g * 128 + h * 4);

        float acc[8];
        #pragma unroll
        for (int e = 0; e < 8; e++) acc[e] = 0.0f;
        #pragma unroll
        for (int e = 0; e < 8; e++) {
            #pragma unroll
            for (int g = 0; g < 6; g++) {
                const float4 w4 = *(const float4*)&wrl[e][g * 128 + h * 4];
                acc[e] = fmaf(xv[g].x, w4.x, acc[e]);
                acc[e] = fmaf(xv[g].y, w4.y, acc[e]);
                acc[e] = fmaf(xv[g].z, w4.z, acc[e]);
                acc[e] = fmaf(xv[g].w, w4.w, acc[e]);
            }
        }
        #pragma unroll
        for (int d = 1; d < 32; d <<= 1) {
            #pragma unroll
            for (int e = 0; e < 8; e++)
                acc[e] += __shfl_xor(acc[e], d);
        }
        float lg[8];
        lg[0] = acc[0] + br[0];
        float m = lg[0]; int am = 0;
        #pragma unroll
        for (int e = 1; e < 8; e++) {
            lg[e] = acc[e] + br[e];
            if (lg[e] > m) { m = lg[e]; am = e; }
        }
        float s = 0.0f;
        #pragma unroll
        for (int e = 0; e < 8; e++) s += expf(lg[e] - m);

        amv[it] = -1;
        if (h == 0) {
            pmax[tok] = 1.0f / s;
            amv[it] = am;
            lpv[it] = atomicAdd(&lcnt[am], 1);
            tkv[it] = tok;
        }
    }
    __syncthreads();
    if (tid < NEXP) gbase[tid] = atomicAdd(&counts[tid * 32], lcnt[tid]);
    __syncthreads();
    #pragma unroll
    for (int it = 0; it < 2; it++)
        if (amv[it] >= 0)
            lists[amv[it] * NTOK + gbase[amv[it]] + lpv[it]] = tkv[it];
}

// ---------------------------------------------------------------------------
// mm12 v3: fused expert FFN with COALESCED LDS staging of x.
// Old mm1/mm12 gathered x at 32B/lane (16 lines touched per instr, ~1.6TB/s).
// Now: per 16-token strip, wave wv stages rows [wv*4, wv*4+4) with contiguous
// 1KB-per-instruction float4 reads, f16-convert -> xt[16][776] (stride =
// 97 x 16B -> ds_read_b128 A-frags land balanced on banks).
// Phase A: wave wv owns r-cols [wv*16,+16) x full K=768 (24 MFMA, B-rows from
// L2-resident w1t). No K-split, no partial-reduce LDS round trip.
// Phase B: R3-proven body, wave wv owns n in [wv*192,+192), A from hl.
// 2 barriers/strip, LDS 27.3KB -> 4 blocks/CU, grid (8,128) = 1024 blocks.
// h never goes to HBM; mm1/mm2 merge also drops one launch boundary.
// ---------------------------------------------------------------------------
__global__ __launch_bounds__(256, 4) void mm12_kernel(
    const float* __restrict__ x, const _Float16* __restrict__ w1t,
    const float* __restrict__ b1, const _Float16* __restrict__ w2t,
    const float* __restrict__ b2, const float* __restrict__ pmax,
    const int* __restrict__ counts, const int* __restrict__ lists,
    float* __restrict__ out)
{
    __shared__ __align__(16) _Float16 xt[16][776];   // 24832 B
    __shared__ __align__(16) _Float16 hl[16][72];    //  2304 B
    __shared__ float pml[16];
    __shared__ int tkl[16];

    const int e = blockIdx.x;
    const int cnt = counts[e * 32];
    const int tid = threadIdx.x;
    const int wv = tid >> 6, lane = tid & 63;
    const int q = lane >> 4, c = lane & 15;

    for (int st = blockIdx.y; st * 16 < cnt; st += gridDim.y) {
        const int base = st * 16;
        const int nt = cnt - base;

        if (tid < 16) {
            const int t = lists[e * NTOK + base + min(tid, nt - 1)];
            tkl[tid] = t;
            pml[tid] = pmax[t];
        }

        // ---- stage x strip -> LDS f16; 1KB contiguous per instruction ----
        #pragma unroll
        for (int rr = 0; rr < 4; rr++) {
            const int row = wv * 4 + rr;
            const int tok = lists[e * NTOK + base + min(row, nt - 1)];
            const float* xr = x + (size_t)tok * HDIM;
            #pragma unroll
            for (int j = 0; j < 3; j++) {
                float4 v = *(const float4*)(xr + j * 256 + lane * 4);
                union { _Float16 hv[4]; unsigned long long u; } pk;
                pk.hv[0] = (_Float16)v.x; pk.hv[1] = (_Float16)v.y;
                pk.hv[2] = (_Float16)v.z; pk.hv[3] = (_Float16)v.w;
                *(unsigned long long*)&xt[row][j * 256 + lane * 4] = pk.u;
            }
        }
        __syncthreads();

        // ---- phase A: wave wv -> r-cols [wv*16,+16), K=768 from LDS ----
        {
            const _Float16* wbase =
                w1t + ((size_t)(e * RDIM + wv * 16 + c)) * HDIM + q * 8;
            float4_t acc = {0, 0, 0, 0};
            #pragma unroll 6
            for (int k0 = 0; k0 < HDIM; k0 += 32) {
                half8 a = *(const half8*)&xt[c][k0 + q * 8];
                half8 b = *(const half8*)(wbase + k0);
                acc = __builtin_amdgcn_mfma_f32_16x16x32_f16(a, b, acc, 0, 0, 0);
            }
            const float b1v = b1[e * RDIM + wv * 16 + c];
            #pragma unroll
            for (int i = 0; i < 4; i++)
                hl[q * 4 + i][wv * 16 + c] = (_Float16)gelu_exact(acc[i] + b1v);
        }
        __syncthreads();

        // ---- phase B (R3-proven): wave wv -> n in [wv*192,+192) ----
        {
            half8 a0 = *(const half8*)&hl[c][q * 8];
            half8 a1 = *(const half8*)&hl[c][32 + q * 8];
            int tokv[4]; float pm[4]; bool ok[4];
            #pragma unroll
            for (int i = 0; i < 4; i++) {
                const int row = q * 4 + i;
                ok[i] = row < nt;
                tokv[i] = tkl[row];
                pm[i] = pml[row];
            }
            #pragma unroll 4
            for (int nf = 0; nf < 12; nf++) {
                const int n = wv * 192 + nf * 16 + c;
                const _Float16* wrow = w2t + ((size_t)(e * HDIM + n)) * RDIM;
                half8 b0  = *(const half8*)(wrow + q * 8);
                half8 b1h = *(const half8*)(wrow + 32 + q * 8);
                float4_t acc2 = {0, 0, 0, 0};
                acc2 = __builtin_amdgcn_mfma_f32_16x16x32_f16(a0, b0, acc2, 0, 0, 0);
                acc2 = __builtin_amdgcn_mfma_f32_16x16x32_f16(a1, b1h, acc2, 0, 0, 0);
                const float b2v = b2[e * HDIM + n];
                #pragma unroll
                for (int i = 0; i < 4; i++) {
                    if (ok[i])
                        out[(size_t)tokv[i] * HDIM + n] = (acc2[i] + b2v) * pm[i];
                }
            }
        }
        __syncthreads();   // xt/hl reused next strip
    }
}

extern "C" void kernel_launch(void* const* d_in, const int* in_sizes, int n_in,
                              void* d_out, int out_size, void* d_ws, size_t ws_size,
                              hipStream_t stream) {
    const float* x     = (const float*)d_in[0];
    const float* enc_w = (const float*)d_in[1];
    const float* enc_b = (const float*)d_in[2];
    const float* sw_w  = (const float*)d_in[3];
    const float* sw_b  = (const float*)d_in[4];
    const float* w1    = (const float*)d_in[5];
    const float* b1    = (const float*)d_in[6];
    const float* w2    = (const float*)d_in[7];
    const float* b2    = (const float*)d_in[8];
    float* out = (float*)d_out;

    // ws layout (~2.2 MB):
    //   [0,1K)          counts (8 ints, 128B stride)
    //   [1K,66560)      pmax 16384 f32
    //   [66560,590848)  lists 8*16384 i32
    //   [590848,...)    wrt (24K), brr (256B), w1t (768K), w2t (768K)
    char* p = (char*)d_ws;
    int*      counts = (int*)p;
    float*    pmax   = (float*)(p + 1024);
    int*      lists  = (int*)(p + 66560);
    float*    wrt    = (float*)(p + 590848);
    float*    brr    = (float*)(p + 615424);
    _Float16* w1t    = (_Float16*)(p + 615680);
    _Float16* w2t    = (_Float16*)(p + 1402112);

    hipMemsetAsync(d_ws, 0, 1024, stream);

    hipLaunchKernelGGL(prep_kernel, dim3(409), dim3(256), 0, stream,
                       w1, w2, enc_w, enc_b, sw_w, sw_b, w1t, w2t, wrt, brr);
    hipLaunchKernelGGL(router_kernel, dim3(NTOK / 16), dim3(256), 0, stream,
                       x, wrt, brr, pmax, counts, lists);
    hipLaunchKernelGGL(mm12_kernel, dim3(NEXP, 128), dim3(256), 0, stream,
                       x, w1t, b1, w2t, b2, pmax, counts, lists, out);
}

// Round 10
// 180.206 us; speedup vs baseline: 2.3009x; 1.0261x over previous
//
#include <hip/hip_runtime.h>
#include <math.h>

#define HDIM 768
#define RDIM 64
#define NEXP 8
#define NTOK 16384

typedef _Float16 half8 __attribute__((ext_vector_type(8)));
typedef float float4_t __attribute__((ext_vector_type(4)));

__device__ __forceinline__ float gelu_exact(float v) {
    return 0.5f * v * (1.0f + erff(v * 0.70710678118654752440f));
}

// ---------------------------------------------------------------------------
// prep (R6-proven, unchanged).
// ---------------------------------------------------------------------------
__global__ __launch_bounds__(256) void prep_kernel(
    const float* __restrict__ w1, const float* __restrict__ w2,
    const float* __restrict__ enc_w, const float* __restrict__ enc_b,
    const float* __restrict__ sw_w, const float* __restrict__ sw_b,
    _Float16* __restrict__ w1t, _Float16* __restrict__ w2t,
    float* __restrict__ wrt, float* __restrict__ brr)
{
    const int wid = blockIdx.x * 4 + (threadIdx.x >> 6);
    const int lane = threadIdx.x & 63;
    if (wid < 768) {
        const int e = wid / 96, k0 = (wid % 96) * 8;
        half8 o;
        #pragma unroll
        for (int j = 0; j < 8; j++)
            o[j] = (_Float16)w1[((size_t)(e * HDIM + k0 + j)) * RDIM + lane];
        *(half8*)(w1t + ((size_t)(e * RDIM + lane)) * HDIM + k0) = o;
    } else if (wid < 1536) {
        const int id = wid - 768;
        const int e = id / 96, rem = id % 96;
        const int n = (rem >> 3) * 64 + lane, k0 = (rem & 7) * 8;
        half8 o;
        #pragma unroll
        for (int j = 0; j < 8; j++)
            o[j] = (_Float16)w2[((size_t)(e * RDIM + k0 + j)) * HDIM + n];
        *(half8*)(w2t + ((size_t)(e * HDIM + n)) * RDIM + k0) = o;
    } else if (wid < 1632) {
        const int k = (wid - 1536) * 8 + (lane >> 3);
        const int e = lane & 7;
        float s = 0.0f;
        #pragma unroll 16
        for (int r = 0; r < RDIM; r++)
            s += enc_w[(size_t)k * RDIM + r] * sw_w[r * NEXP + e];
        wrt[e * HDIM + k] = s;
    } else if (wid == 1632) {
        if (lane < NEXP) {
            float s = sw_b[lane];
            #pragma unroll 16
            for (int r = 0; r < RDIM; r++)
                s += enc_b[r] * sw_w[r * NEXP + lane];
            brr[lane] = s;
        }
    }
}

// ---------------------------------------------------------------------------
// router v4 (R6-proven, unchanged).
// ---------------------------------------------------------------------------
__global__ __launch_bounds__(256, 4) void router_kernel(
    const float* __restrict__ x, const float* __restrict__ wrt,
    const float* __restrict__ brr, float* __restrict__ pmax,
    int* __restrict__ counts, int* __restrict__ lists)
{
    __shared__ __align__(16) float wrl[NEXP][772];
    __shared__ int lcnt[NEXP], gbase[NEXP];

    const int tid = threadIdx.x;
    #pragma unroll
    for (int i0 = 0; i0 < 6; i0++) {
        const int i = tid + i0 * 256;
        const int e = i / 192, k4 = (i % 192) * 4;
        *(float4*)&wrl[e][k4] = *(const float4*)(wrt + e * HDIM + k4);
    }
    if (tid < NEXP) lcnt[tid] = 0;

    const int wv = tid >> 6, lane = tid & 63;
    const int h = lane & 31, hw = lane >> 5;

    float br[8];
    #pragma unroll
    for (int e = 0; e < 8; e++) br[e] = brr[e];
    __syncthreads();

    int amv[2], lpv[2], tkv[2];
    #pragma unroll
    for (int it = 0; it < 2; it++) {
        const int tok = blockIdx.x * 16 + it * 8 + wv * 2 + hw;
        const float* xrow = x + (size_t)tok * HDIM;
        float4 xv[6];
        #pragma unroll
        for (int g = 0; g < 6; g++)
            xv[g] = *(const float4*)(xrow + g * 128 + h * 4);

        float acc[8];
        #pragma unroll
        for (int e = 0; e < 8; e++) acc[e] = 0.0f;
        #pragma unroll
        for (int e = 0; e < 8; e++) {
            #pragma unroll
            for (int g = 0; g < 6; g++) {
                const float4 w4 = *(const float4*)&wrl[e][g * 128 + h * 4];
                acc[e] = fmaf(xv[g].x, w4.x, acc[e]);
                acc[e] = fmaf(xv[g].y, w4.y, acc[e]);
                acc[e] = fmaf(xv[g].z, w4.z, acc[e]);
                acc[e] = fmaf(xv[g].w, w4.w, acc[e]);
            }
        }
        #pragma unroll
        for (int d = 1; d < 32; d <<= 1) {
            #pragma unroll
            for (int e = 0; e < 8; e++)
                acc[e] += __shfl_xor(acc[e], d);
        }
        float lg[8];
        lg[0] = acc[0] + br[0];
        float m = lg[0]; int am = 0;
        #pragma unroll
        for (int e = 1; e < 8; e++) {
            lg[e] = acc[e] + br[e];
            if (lg[e] > m) { m = lg[e]; am = e; }
        }
        float s = 0.0f;
        #pragma unroll
        for (int e = 0; e < 8; e++) s += expf(lg[e] - m);

        amv[it] = -1;
        if (h == 0) {
            pmax[tok] = 1.0f / s;
            amv[it] = am;
            lpv[it] = atomicAdd(&lcnt[am], 1);
            tkv[it] = tok;
        }
    }
    __syncthreads();
    if (tid < NEXP) gbase[tid] = atomicAdd(&counts[tid * 32], lcnt[tid]);
    __syncthreads();
    #pragma unroll
    for (int it = 0; it < 2; it++)
        if (amv[it] >= 0)
            lists[amv[it] * NTOK + gbase[amv[it]] + lpv[it]] = tkv[it];
}

// ---------------------------------------------------------------------------
// mm12 v4 = v3 (coalesced x staging, R9: FETCH 45->26MB ideal) + LDS-staged
// COALESCED out stores. R9 showed bytes are now ideal (76MB) but rate is
// 1.15TB/s; prime suspect is the 64B-per-row scattered store drain.
// obuf[16][780] f32 UNIONS with xt (xt dead after phase A): LDS 52.4KB,
// 3 blocks/CU. Pad 780: phase-B writes land 2-way bank-aliased (free);
// store loop reads sequential float4 (conflict-free) and writes each token
// row as 3KB contiguous (1KB per wave-instruction, 24 full lines/row).
// Fork documented in journal: if dur stays >=60us, stores weren't the cap
// -> R11 pivots to 2-strip async pipelining.
// ---------------------------------------------------------------------------
__global__ __launch_bounds__(256, 3) void mm12_kernel(
    const float* __restrict__ x, const _Float16* __restrict__ w1t,
    const float* __restrict__ b1, const _Float16* __restrict__ w2t,
    const float* __restrict__ b2, const float* __restrict__ pmax,
    const int* __restrict__ counts, const int* __restrict__ lists,
    float* __restrict__ out)
{
    // union: xt[16][776] f16 (24832B) | obuf[16][780] f32 (49920B)
    __shared__ __align__(16) char smemU[16 * 780 * 4];
    _Float16 (*xt)[776] = (_Float16 (*)[776])smemU;
    float (*obuf)[780]  = (float (*)[780])smemU;
    __shared__ __align__(16) _Float16 hl[16][72];
    __shared__ float pml[16];
    __shared__ int tkl[16];

    const int e = blockIdx.x;
    const int cnt = counts[e * 32];
    const int tid = threadIdx.x;
    const int wv = tid >> 6, lane = tid & 63;
    const int q = lane >> 4, c = lane & 15;

    for (int st = blockIdx.y; st * 16 < cnt; st += gridDim.y) {
        const int base = st * 16;
        const int nt = cnt - base;

        if (tid < 16) {
            const int t = lists[e * NTOK + base + min(tid, nt - 1)];
            tkl[tid] = t;
            pml[tid] = pmax[t];
        }

        // ---- stage x strip -> LDS f16; 1KB contiguous per instruction ----
        #pragma unroll
        for (int rr = 0; rr < 4; rr++) {
            const int row = wv * 4 + rr;
            const int tok = lists[e * NTOK + base + min(row, nt - 1)];
            const float* xr = x + (size_t)tok * HDIM;
            #pragma unroll
            for (int j = 0; j < 3; j++) {
                float4 v = *(const float4*)(xr + j * 256 + lane * 4);
                union { _Float16 hv[4]; unsigned long long u; } pk;
                pk.hv[0] = (_Float16)v.x; pk.hv[1] = (_Float16)v.y;
                pk.hv[2] = (_Float16)v.z; pk.hv[3] = (_Float16)v.w;
                *(unsigned long long*)&xt[row][j * 256 + lane * 4] = pk.u;
            }
        }
        __syncthreads();

        // ---- phase A: wave wv -> r-cols [wv*16,+16), K=768 from LDS ----
        {
            const _Float16* wbase =
                w1t + ((size_t)(e * RDIM + wv * 16 + c)) * HDIM + q * 8;
            float4_t acc = {0, 0, 0, 0};
            #pragma unroll 6
            for (int k0 = 0; k0 < HDIM; k0 += 32) {
                half8 a = *(const half8*)&xt[c][k0 + q * 8];
                half8 b = *(const half8*)(wbase + k0);
                acc = __builtin_amdgcn_mfma_f32_16x16x32_f16(a, b, acc, 0, 0, 0);
            }
            const float b1v = b1[e * RDIM + wv * 16 + c];
            #pragma unroll
            for (int i = 0; i < 4; i++)
                hl[q * 4 + i][wv * 16 + c] = (_Float16)gelu_exact(acc[i] + b1v);
        }
        __syncthreads();   // xt reads done -> smemU may become obuf

        // ---- phase B: wave wv -> n in [wv*192,+192); results -> obuf ----
        {
            half8 a0 = *(const half8*)&hl[c][q * 8];
            half8 a1 = *(const half8*)&hl[c][32 + q * 8];
            float pm[4];
            #pragma unroll
            for (int i = 0; i < 4; i++) pm[i] = pml[q * 4 + i];

            #pragma unroll 4
            for (int nf = 0; nf < 12; nf++) {
                const int n = wv * 192 + nf * 16 + c;
                const _Float16* wrow = w2t + ((size_t)(e * HDIM + n)) * RDIM;
                half8 b0  = *(const half8*)(wrow + q * 8);
                half8 b1h = *(const half8*)(wrow + 32 + q * 8);
                float4_t acc2 = {0, 0, 0, 0};
                acc2 = __builtin_amdgcn_mfma_f32_16x16x32_f16(a0, b0, acc2, 0, 0, 0);
                acc2 = __builtin_amdgcn_mfma_f32_16x16x32_f16(a1, b1h, acc2, 0, 0, 0);
                const float b2v = b2[e * HDIM + n];
                #pragma unroll
                for (int i = 0; i < 4; i++)
                    obuf[q * 4 + i][n] = (acc2[i] + b2v) * pm[i];
            }
        }
        __syncthreads();

        // ---- coalesced store: 16 rows x 768 f32; 1KB/wave-instruction ----
        #pragma unroll
        for (int j = 0; j < 12; j++) {
            const int idx = j * 256 + tid;          // 0..3071
            const int row = idx / 192;
            const int c4  = idx - row * 192;
            if (row < nt) {
                float4_t v = *(const float4_t*)&obuf[row][c4 * 4];
                *(float4_t*)(out + (size_t)tkl[row] * HDIM + c4 * 4) = v;
            }
        }
        __syncthreads();   // smemU reused (as xt) next strip
    }
}

extern "C" void kernel_launch(void* const* d_in, const int* in_sizes, int n_in,
                              void* d_out, int out_size, void* d_ws, size_t ws_size,
                              hipStream_t stream) {
    const float* x     = (const float*)d_in[0];
    const float* enc_w = (const float*)d_in[1];
    const float* enc_b = (const float*)d_in[2];
    const float* sw_w  = (const float*)d_in[3];
    const float* sw_b  = (const float*)d_in[4];
    const float* w1    = (const float*)d_in[5];
    const float* b1    = (const float*)d_in[6];
    const float* w2    = (const float*)d_in[7];
    const float* b2    = (const float*)d_in[8];
    float* out = (float*)d_out;

    // ws layout (~2.2 MB):
    //   [0,1K)          counts (8 ints, 128B stride)
    //   [1K,66560)      pmax 16384 f32
    //   [66560,590848)  lists 8*16384 i32
    //   [590848,...)    wrt (24K), brr (256B), w1t (768K), w2t (768K)
    char* p = (char*)d_ws;
    int*      counts = (int*)p;
    float*    pmax   = (float*)(p + 1024);
    int*      lists  = (int*)(p + 66560);
    float*    wrt    = (float*)(p + 590848);
    float*    brr    = (float*)(p + 615424);
    _Float16* w1t    = (_Float16*)(p + 615680);
    _Float16* w2t    = (_Float16*)(p + 1402112);

    hipMemsetAsync(d_ws, 0, 1024, stream);

    hipLaunchKernelGGL(prep_kernel, dim3(409), dim3(256), 0, stream,
                       w1, w2, enc_w, enc_b, sw_w, sw_b, w1t, w2t, wrt, brr);
    hipLaunchKernelGGL(router_kernel, dim3(NTOK / 16), dim3(256), 0, stream,
                       x, wrt, brr, pmax, counts, lists);
    hipLaunchKernelGGL(mm12_kernel, dim3(NEXP, 128), dim3(256), 0, stream,
                       x, w1t, b1, w2t, b2, pmax, counts, lists, out);
}